// Round 1
// baseline (409.500 us; speedup 1.0000x reference)
//
#include <hip/hip_runtime.h>

#define NXD 512
#define NYD 512

// Zero the output canvas (float4 stores) and init winner array to -1 (int4).
__global__ void ppscatter_zero_init(float4* __restrict__ out4, long n_out4,
                                    int4* __restrict__ win4, long n_win4) {
    long i = (long)blockIdx.x * blockDim.x + threadIdx.x;
    if (i < n_out4) out4[i] = make_float4(0.f, 0.f, 0.f, 0.f);
    if (i < n_win4) win4[i] = make_int4(-1, -1, -1, -1);
}

// Last-write-wins vote: max voxel index per flat slot wins (matches numpy
// fancy-assignment semantics where the last duplicate index wins).
__global__ void ppscatter_vote(const int* __restrict__ coords, int n,
                               int* __restrict__ winner) {
    int v = blockIdx.x * blockDim.x + threadIdx.x;
    if (v >= n) return;
    int b = coords[3 * v + 0];
    int x = coords[3 * v + 1];
    int y = coords[3 * v + 2];
    int flat = b * (NXD * NYD) + x * NYD + y;
    atomicMax(&winner[flat], v);
}

// One 64-lane wave per voxel; lane c handles channel c.
// Reads are coalesced (256 B per wave); writes are 4 B scattered, strided
// NX*NY floats apart (the [B,C,NX,NY] transpose makes this unavoidable).
__global__ void ppscatter_scatter(const float* __restrict__ feat,
                                  const int* __restrict__ coords,
                                  const int* __restrict__ winner,
                                  float* __restrict__ out,
                                  int n, int C) {
    int gtid = blockIdx.x * blockDim.x + threadIdx.x;
    int v = gtid >> 6;          // wave index = voxel index
    int lane = gtid & 63;       // lane = channel
    if (v >= n) return;
    int b = coords[3 * v + 0];
    int x = coords[3 * v + 1];
    int y = coords[3 * v + 2];
    int flat = b * (NXD * NYD) + x * NYD + y;
    if (winner[flat] != v) return;   // lost the duplicate race -> skip
    long xy = (long)x * NYD + y;
    long base = (long)b * C * (NXD * NYD);
    for (int c = lane; c < C; c += 64) {
        out[base + (long)c * (NXD * NYD) + xy] = feat[(long)v * C + c];
    }
}

extern "C" void kernel_launch(void* const* d_in, const int* in_sizes, int n_in,
                              void* d_out, int out_size, void* d_ws, size_t ws_size,
                              hipStream_t stream) {
    const float* feat  = (const float*)d_in[0];
    const int* coords  = (const int*)d_in[1];
    // d_in[2] = batch_size scalar; implied by out_size, unused.

    int n = in_sizes[1] / 3;            // number of voxels
    int C = in_sizes[0] / n;            // channels (64)
    float* out = (float*)d_out;
    int* winner = (int*)d_ws;           // B*NX*NY ints = 4 MiB

    long rows   = (long)out_size / C;   // B*NX*NY canvas rows
    long n_out4 = (long)out_size / 4;
    long n_win4 = rows / 4;

    const int T = 256;
    long maxn = n_out4 > n_win4 ? n_out4 : n_win4;
    int grid0 = (int)((maxn + T - 1) / T);
    ppscatter_zero_init<<<grid0, T, 0, stream>>>((float4*)d_out, n_out4,
                                                 (int4*)winner, n_win4);

    int grid1 = (n + T - 1) / T;
    ppscatter_vote<<<grid1, T, 0, stream>>>(coords, n, winner);

    long scatter_threads = (long)n * 64;
    int grid2 = (int)((scatter_threads + T - 1) / T);
    ppscatter_scatter<<<grid2, T, 0, stream>>>(feat, coords, winner, out, n, C);
}

// Round 2
// 294.544 us; speedup vs baseline: 1.3903x; 1.3903x over previous
//
#include <hip/hip_runtime.h>

#define NXD 512
#define NYD 512
// Problem constants (fixed by the reference): B=4, C=64, NX=NY=512.

// Init winner array to -1 (int4 stores).
__global__ void ppscatter_init_winner(int4* __restrict__ win4, int n_win4) {
    int i = blockIdx.x * blockDim.x + threadIdx.x;
    if (i < n_win4) win4[i] = make_int4(-1, -1, -1, -1);
}

// Last-write-wins vote: max voxel index per flat slot wins (matches numpy
// fancy-assignment semantics where the last duplicate index wins; verified
// absmax=0.0 in round 1).
__global__ void ppscatter_vote(const int* __restrict__ coords, int n,
                               int* __restrict__ winner) {
    int v = blockIdx.x * blockDim.x + threadIdx.x;
    if (v >= n) return;
    int b = coords[3 * v + 0];
    int x = coords[3 * v + 1];
    int y = coords[3 * v + 2];
    atomicMax(&winner[b * (NXD * NYD) + x * NYD + y], v);
}

// Gather: one thread per output float4. Thread i maps directly to
// out4[i] with i = (b<<22)|(c<<16)|(x<<7)|y4  (C=64, NX=NY=512).
// Writes are perfectly coalesced (1 KB/wave); winner reads coalesced int4;
// feature reads are scattered scalar but only for ~1.9% of pixels and
// feat (20.5 MB) is L2/L3-resident.
__global__ void ppscatter_gather(const float* __restrict__ feat,
                                 const int* __restrict__ winner,
                                 float4* __restrict__ out4) {
    int i = blockIdx.x * blockDim.x + threadIdx.x;  // 16,777,216 threads
    int y4 = i & 127;
    int x  = (i >> 7) & 511;
    int c  = (i >> 16) & 63;
    int b  = i >> 22;

    const int4* win4 = (const int4*)winner;
    int4 w = win4[(b << 16) | (x << 7) | y4];   // winner[b][x][y4*4 .. +3]

    float4 val = make_float4(0.f, 0.f, 0.f, 0.f);
    // All-empty fast path: winner entries are -1 or >=0; AND == -1 iff all -1.
    if ((w.x & w.y & w.z & w.w) != -1) {
        if (w.x >= 0) val.x = feat[(w.x << 6) + c];
        if (w.y >= 0) val.y = feat[(w.y << 6) + c];
        if (w.z >= 0) val.z = feat[(w.z << 6) + c];
        if (w.w >= 0) val.w = feat[(w.w << 6) + c];
    }
    out4[i] = val;
}

extern "C" void kernel_launch(void* const* d_in, const int* in_sizes, int n_in,
                              void* d_out, int out_size, void* d_ws, size_t ws_size,
                              hipStream_t stream) {
    const float* feat  = (const float*)d_in[0];
    const int* coords  = (const int*)d_in[1];

    int n = in_sizes[1] / 3;            // 80000 voxels
    int* winner = (int*)d_ws;           // B*NX*NY ints = 4 MiB scratch

    const int T = 256;

    int n_win4 = (4 * NXD * NYD) / 4;   // 262144
    ppscatter_init_winner<<<(n_win4 + T - 1) / T, T, 0, stream>>>((int4*)winner, n_win4);

    ppscatter_vote<<<(n + T - 1) / T, T, 0, stream>>>(coords, n, winner);

    int n_out4 = out_size / 4;          // 16,777,216
    ppscatter_gather<<<n_out4 / T, T, 0, stream>>>(feat, winner, (float4*)d_out);
}